// Round 4
// baseline (162.112 us; speedup 1.0000x reference)
//
#include <hip/hip_runtime.h>

// AnomalyAttention: B=16, L=512, H=8, E=D=64. f32 in/out, bf16 MFMA compute.
// Transposed formulation: S^T = K.Q^T (D: row=s, col=l), out^T = V^T.W^T.
// e round-trips LDS as packed bf16 dwords. R9: prior p computed directly in
// B-operand layout per lane. Uniform 8-iteration loop, 2 barriers/iter (R5).
// R12: T14 issue-early/write-late prefetch, no loop-carried staging regs.
// R13 (work-balanced paired blocks + shared staging): R12 was neutral vs R9
//   with clean traffic -> load latency exonerated; the cost is structural:
//   per-block work varied 8x (t+1 live tiles), so the t=7 blocks finish their
//   last iterations on a near-empty CU (VALUBusy 25%, Occ 24%), and each
//   t-block staged its own K/V copy (36 tile-stages per bh for 8 tiles).
//   Fix: ONE 512-thread block = l-tile z (waves 0-3) + l-tile 7-z (waves 4-7)
//   sharing a single K/V LDS copy (lo s-range is a subset of hi s-range).
//   Every block = exactly 9 live wave-tile units -> no tail. Threads <256
//   stage K, threads >=256 stage V -> per-thread staging halves, each staged
//   tile feeds 2x compute. Grid 512 = 2 blocks/CU, 16 waves/CU sustained;
//   same-bh blocks XCD-affine (z stride 128 == 0 mod 8). Predicates:
//   K iff tile <= 7-z; V iff tile <= 8-z (prior band is exactly
//   tile in [t-1,t+1]: delta = 64*(tile-t)-16*wg must lie in [-127,79]).
// out = [ g*(e@V)/E + (1-g)*(p@V)/(P+1e-8) ] / (Sf+1e-8); E,P = sums of
// truncated-bf16 e,p (exactly the MFMA operands).

#define B_ 16
#define L_ 512
#define H_ 8
#define KST 72   // K LDS row stride (shorts)
#define VST 72   // V^T LDS row stride (shorts)
#define WST 36   // We LDS row stride (dwords), 16 rows/wave

typedef __attribute__((ext_vector_type(8))) short bf16x8;
typedef __attribute__((ext_vector_type(4))) float f32x4;
union FR { bf16x8 v; unsigned u[4]; uint4 q4; };

static __device__ __forceinline__ unsigned fbits(float x){union{float f;unsigned u;}c;c.f=x;return c.u;}
static __device__ __forceinline__ float tvf(float x){union{unsigned u;float f;}c;c.u=fbits(x)&0xFFFF0000u;return c.f;}
// pack trunc-bf16(a) | trunc-bf16(b)<<16 in one v_perm_b32
static __device__ __forceinline__ unsigned pk2(float a,float b){return __builtin_amdgcn_perm(fbits(b),fbits(a),0x07060302u);}

// Block barrier with LDS-drain only: does NOT wait vmcnt, so register-staged
// global prefetch loads remain in flight across it (T4). The "memory"
// clobbers fence the compiler from moving LDS/global ops across the barrier.
static __device__ __forceinline__ void barrier_lgkm(){
  asm volatile("s_waitcnt lgkmcnt(0)" ::: "memory");
  __builtin_amdgcn_s_barrier();
  asm volatile("" ::: "memory");
}

__global__ __launch_bounds__(512,4) void anomaly_attn(
    const float* __restrict__ Q, const float* __restrict__ K,
    const float* __restrict__ V, const float* __restrict__ Sig,
    const float* __restrict__ Gate, float* __restrict__ Out)
{
  __shared__ unsigned short Klds[64*KST];   // 9216 B (shared by both l-groups)
  __shared__ unsigned short Vlds[64*VST];   // 9216 B (V^T, granule-swizzled)
  __shared__ unsigned We[8][16][WST];       // 18432 B packed e pairs (wave-private)

  const int tid=threadIdx.x, lane=tid&63, wid=tid>>6, q=lane>>4, c=lane&15;
  const int idx=blockIdx.x, bh=idx&127, z=idx>>7, h=bh&7, b=bh>>3;
  const int grp=wid>>2, wg=wid&3;
  const int t = grp ? (7-z) : z;            // this wave's l-tile
  const int l0w = t*64 + wg*16;             // wave's 16 l-rows: l = l0w + c
  const size_t bh_off = ((size_t)b*L_*H_ + h)*64;
  const float* __restrict__ Qb=Q+bh_off;
  const float* __restrict__ Kb=K+bh_off;
  const float* __restrict__ Vb=V+bh_off;

  // staging roles: threads <256 stage K, threads >=256 stage V
  const bool isK = tid<256;
  const int thr = tid&255;
  const int kr=thr>>2, kcb=thr&3;           // K role: row kr, 16 floats at kcb*16
  const int srp=thr>>3, scb=thr&7;          // V role: rows 2srp..+1, 8 floats at scb*8
  const int swz = (c&3)<<3;                 // We column XOR swizzle
  const int gp=(srp>>2)^scb, rpl=srp&3, vb0i=(gp<<3);  // V pack mapping

  const float* __restrict__ vbase = Vb + (size_t)(2*srp)*512 + scb*8;
  const float* __restrict__ kbase = Kb + (size_t)kr*512 + kcb*16;

  // ---- prologue: load + pack tile 0 by role (always needed) ----
  if (isK) {
    float4 g0=((const float4*)kbase)[0], g1=((const float4*)kbase)[1];
    float4 g2=((const float4*)kbase)[2], g3=((const float4*)kbase)[3];
    uint4 w0,w1;
    w0.x=pk2(g0.x,g0.y); w0.y=pk2(g0.z,g0.w);
    w0.z=pk2(g1.x,g1.y); w0.w=pk2(g1.z,g1.w);
    w1.x=pk2(g2.x,g2.y); w1.y=pk2(g2.z,g2.w);
    w1.z=pk2(g3.x,g3.y); w1.w=pk2(g3.z,g3.w);
    uint4* dst=(uint4*)&Klds[kr*KST + kcb*16];
    dst[0]=w0; dst[1]=w1;
  } else {
    float4 g0=((const float4*)vbase)[0],       g1=((const float4*)vbase)[1];
    float4 g2=((const float4*)(vbase+512))[0], g3=((const float4*)(vbase+512))[1];
    ((unsigned*)&Vlds[(scb*8+0)*VST+vb0i])[rpl]=pk2(g0.x,g2.x);
    ((unsigned*)&Vlds[(scb*8+1)*VST+vb0i])[rpl]=pk2(g0.y,g2.y);
    ((unsigned*)&Vlds[(scb*8+2)*VST+vb0i])[rpl]=pk2(g0.z,g2.z);
    ((unsigned*)&Vlds[(scb*8+3)*VST+vb0i])[rpl]=pk2(g0.w,g2.w);
    ((unsigned*)&Vlds[(scb*8+4)*VST+vb0i])[rpl]=pk2(g1.x,g3.x);
    ((unsigned*)&Vlds[(scb*8+5)*VST+vb0i])[rpl]=pk2(g1.y,g3.y);
    ((unsigned*)&Vlds[(scb*8+6)*VST+vb0i])[rpl]=pk2(g1.z,g3.z);
    ((unsigned*)&Vlds[(scb*8+7)*VST+vb0i])[rpl]=pk2(g1.w,g3.w);
  }

  // ---- Q as B-operand frag: lane c -> l, quad*8+j -> e ----
  bf16x8 qf[2];
  {
    const float* qrow = Qb + (size_t)(l0w+c)*512;
    #pragma unroll
    for (int ks=0; ks<2; ++ks) {
      const float4 a = *(const float4*)(qrow + ks*32 + q*8);
      const float4 d4 = *(const float4*)(qrow + ks*32 + q*8 + 4);
      FR f;
      f.u[0]=pk2(a.x,a.y);  f.u[1]=pk2(a.z,a.w);
      f.u[2]=pk2(d4.x,d4.y); f.u[3]=pk2(d4.z,d4.w);
      qf[ks]=f.v;
    }
  }

  // ---- per-lane prior constants (row l = l0w + c) ----
  const float sgv = Sig[((size_t)b*L_ + l0w + c)*H_ + h];
  float sg = 1.f/(1.f+__expf(-5.f*sgv)) + 1e-5f;
  sg = exp2f(sg*1.5849625007211562f) - 1.f;          // 3^sg - 1
  const float invs = 0.3989422804014327f/sg;
  const float i2s2 = (0.5f/(sg*sg))*1.44269504088896f;

  float eP=0.f, pP=0.f;
  f32x4 accA[4], accB[4];
  #pragma unroll
  for (int n=0;n<4;++n){accA[n]=(f32x4)0.f;accB[n]=(f32x4)0.f;}

  for (int tile=0; tile<8; ++tile) {
    const int s0=tile*64;
    const bool live = tile<=t, diag = tile==t;   // wave-uniform
    const int delta = s0 - l0w;                  // wave-uniform
    // prior band per 32-col chunk (s-l range vs |l-s|<=64 support)
    const bool bk0 = (delta    >= -95) && (delta    <= 79);
    const bool bk1 = (delta+32 >= -95) && (delta+32 <= 79);
    barrier_lgkm();   // barrier A: this tile's K/V packs (prev tail) visible

    // ---- issue tile+1 global loads NOW by role (within-iteration liveness,
    //      no loop-carried PHIs); consumed only after barrier B ----
    float4 g0,g1,g2,g3;
    bool need1=false;
    if (tile<7) {
      need1 = isK ? ((tile+1) <= 7-z) : ((tile+1) <= 8-z);
      if (need1) {
        if (isK) {
          const float* kp = kbase + (size_t)(s0+64)*512;
          g0=((const float4*)kp)[0]; g1=((const float4*)kp)[1];
          g2=((const float4*)kp)[2]; g3=((const float4*)kp)[3];
        } else {
          const float* vp = vbase + (size_t)(s0+64)*512;
          g0=((const float4*)vp)[0];       g1=((const float4*)vp)[1];
          g2=((const float4*)(vp+512))[0]; g3=((const float4*)(vp+512))[1];
        }
      }
    }

    // ---- e path: scores S^T then packed bf16 into We (D-layout == B-layout) ----
    int ks2max = -1;
    if (live) {
      const int ntmax = diag ? wg : 3;          // s-chunks with any e!=0
      ks2max = diag ? (wg>>1) : 1;              // s-32-chunks for PV
      f32x4 sacc[4];
      #pragma unroll
      for (int nt=0;nt<4;++nt) if (nt<=ntmax) {
        f32x4 s=(f32x4)0.f;
        #pragma unroll
        for (int ks=0;ks<2;++ks){
          const bf16x8 kf=*(const bf16x8*)&Klds[(nt*16+c)*KST + ks*32 + q*8];
          s=__builtin_amdgcn_mfma_f32_16x16x32_bf16(kf,qf[ks],s,0,0,0); // A=K(m=s),B=Q(n=l)
        }
        sacc[nt]=s;
      }
      #pragma unroll
      for (int nt=0;nt<4;++nt) {
        if (nt<=ntmax) {
          float ev[4];
          #pragma unroll
          for (int r=0;r<4;++r) ev[r]=exp2f(sacc[nt][r]*0.180336880110323f); // exp(s/8)
          if (diag && nt==wg) {                  // per-element causal mask
            #pragma unroll
            for (int r=0;r<4;++r) if (4*q+r > c) ev[r]=0.f;
          }
          #pragma unroll
          for (int r=0;r<4;++r) eP += tvf(ev[r]);  // sum == MFMA operand
          uint2 w; w.x=pk2(ev[0],ev[1]); w.y=pk2(ev[2],ev[3]);
          *(uint2*)&We[wid][c][(nt*8+2*q)^swz]=w;
        } else if (nt <= 2*ks2max+1) {           // zero-fill read-covered chunk
          uint2 zz; zz.x=0u; zz.y=0u;
          *(uint2*)&We[wid][c][(nt*8+2*q)^swz]=zz;
        }
      }
    }
    asm volatile("s_waitcnt lgkmcnt(0)" ::: "memory");  // We visible (wave-
    // private); "memory" also pins the prefetch loads in the first half.

    // ---- PV frags: e from We; p computed directly in B layout ----
    FR ef[2], pf[2];
    #pragma unroll
    for (int k2=0;k2<2;++k2){
      if (k2<=ks2max) ef[k2].q4 = *(const uint4*)&We[wid][c][(k2*16+4*q)^swz];
      if (k2 ? bk1 : bk0) {
        float pv[8];
        #pragma unroll
        for (int j=0;j<8;++j){
          const float dd=(float)(c - k2*32 - q*8 - j - delta);  // l - s
          pv[j]=invs*exp2f(-dd*dd*i2s2);
          pP += tvf(pv[j]);
        }
        pf[k2].u[0]=pk2(pv[0],pv[1]); pf[k2].u[1]=pk2(pv[2],pv[3]);
        pf[k2].u[2]=pk2(pv[4],pv[5]); pf[k2].u[3]=pk2(pv[6],pv[7]);
      }
    }
    // ---- PV: A = V^T (m=d,k=s), B = W (k=s,n=l) ----
    #pragma unroll
    for (int nd=0;nd<4;++nd){
      const int d=nd*16+c, dg7=(d>>3)&7;
      #pragma unroll
      for (int k2=0;k2<2;++k2){
        const bool pb = k2 ? bk1 : bk0;
        if (k2<=ks2max || pb) {
          const int g2i=((k2<<2)+q)^dg7;
          const bf16x8 vf=*(const bf16x8*)&Vlds[d*VST + (g2i<<3)];
          if (k2<=ks2max) accA[nd]=__builtin_amdgcn_mfma_f32_16x16x32_bf16(vf,ef[k2].v,accA[nd],0,0,0);
          if (pb)         accB[nd]=__builtin_amdgcn_mfma_f32_16x16x32_bf16(vf,pf[k2].v,accB[nd],0,0,0);
        }
      }
    }

    barrier_lgkm();   // barrier B: all waves' K/V reads of this tile complete;
                      // prefetch vmem still in flight (non-draining)

    // ---- write-late: pack tile+1 into K/V LDS (vmcnt wait lands here; the
    //      loads had the whole compute phase to arrive) ----
    if (tile<7 && need1) {
      if (isK) {
        uint4 w0,w1;
        w0.x=pk2(g0.x,g0.y); w0.y=pk2(g0.z,g0.w);
        w0.z=pk2(g1.x,g1.y); w0.w=pk2(g1.z,g1.w);
        w1.x=pk2(g2.x,g2.y); w1.y=pk2(g2.z,g2.w);
        w1.z=pk2(g3.x,g3.y); w1.w=pk2(g3.z,g3.w);
        uint4* dst=(uint4*)&Klds[kr*KST + kcb*16];
        dst[0]=w0; dst[1]=w1;
      } else {
        ((unsigned*)&Vlds[(scb*8+0)*VST+vb0i])[rpl]=pk2(g0.x,g2.x);
        ((unsigned*)&Vlds[(scb*8+1)*VST+vb0i])[rpl]=pk2(g0.y,g2.y);
        ((unsigned*)&Vlds[(scb*8+2)*VST+vb0i])[rpl]=pk2(g0.z,g2.z);
        ((unsigned*)&Vlds[(scb*8+3)*VST+vb0i])[rpl]=pk2(g0.w,g2.w);
        ((unsigned*)&Vlds[(scb*8+4)*VST+vb0i])[rpl]=pk2(g1.x,g3.x);
        ((unsigned*)&Vlds[(scb*8+5)*VST+vb0i])[rpl]=pk2(g1.y,g3.y);
        ((unsigned*)&Vlds[(scb*8+6)*VST+vb0i])[rpl]=pk2(g1.z,g3.z);
        ((unsigned*)&Vlds[(scb*8+7)*VST+vb0i])[rpl]=pk2(g1.w,g3.w);
      }
    }
  }

  // ---- epilogue: quad reduce, per-lane scalars, float4 stores ----
  eP += __shfl_xor(eP,16,64); eP += __shfl_xor(eP,32,64);
  pP += __shfl_xor(pP,16,64); pP += __shfl_xor(pP,32,64);
  float g=Gate[h]; g=1.f/(1.f+__expf(-g));
  const float cA=g/eP;                       // E>0 (diagonal always live)
  const float cB=(1.f-g)/(pP+1e-8f);
  const float Sf=g+(1.f-g)*(pP/(pP+1e-8f));
  const float nf=1.f/(Sf+1e-8f);
  #pragma unroll
  for (int nd=0;nd<4;++nd){
    float4 o;
    o.x=(cA*accA[nd][0]+cB*accB[nd][0])*nf;
    o.y=(cA*accA[nd][1]+cB*accB[nd][1])*nf;
    o.z=(cA*accA[nd][2]+cB*accB[nd][2])*nf;
    o.w=(cA*accA[nd][3]+cB*accB[nd][3])*nf;
    *(float4*)&Out[bh_off + (size_t)(l0w+c)*512 + nd*16 + 4*q] = o;
  }
}

extern "C" void kernel_launch(void* const* d_in, const int* in_sizes, int n_in,
                              void* d_out, int out_size, void* d_ws, size_t ws_size,
                              hipStream_t stream) {
    const float* Q    = (const float*)d_in[0];
    const float* K    = (const float*)d_in[1];
    const float* V    = (const float*)d_in[2];
    const float* Sig  = (const float*)d_in[3];
    const float* Gate = (const float*)d_in[4];
    // d_in[5] = attn_mask: deterministic causal triu — not read.
    float* Out = (float*)d_out;

    dim3 grid(4 * B_ * H_);   // 512 blocks: idx = z*128 + bh; z pairs l-tiles
                              // (z, 7-z) -> every block = 9 live wave-tile
                              // units; same-bh blocks XCD-affine (128%8==0)
    anomaly_attn<<<grid, 512, 0, stream>>>(Q, K, V, Sig, Gate, Out);
}

// Round 5
// 144.094 us; speedup vs baseline: 1.1250x; 1.1250x over previous
//
#include <hip/hip_runtime.h>

// AnomalyAttention: B=16, L=512, H=8, E=D=64. f32 in/out, bf16 MFMA compute.
// Transposed formulation: S^T = K.Q^T (D: row=s, col=l), out^T = V^T.W^T.
// e round-trips LDS as packed bf16 dwords. R9: prior p computed directly in
// B-operand layout per lane. Uniform 8-iteration loop, 2 barriers/iter (R5).
// R12: T14 issue-early/write-late prefetch, no loop-carried staging regs.
// R13 (work-balanced paired blocks + shared staging): ONE 512-thread block =
//   l-tile z (waves 0-3) + l-tile 7-z (waves 4-7) sharing a single K/V LDS
//   copy. Every block = exactly 9 live wave-tile units -> no retire tail
//   (confirmed: Occ 24->37%). Threads <256 stage K, >=256 stage V.
// R14 (fix R13's spill): launch_bounds(512,4) capped the UNIFIED reg file at
//   128/wave; kernel needs ~80 arch VGPR + 64 acc ~= 144 -> allocator pinned
//   VGPR=64 and spilled staging (WRITE_SIZE 44MB, 75us). (512,2) lifts the
//   cap to 256; residency is grid-limited at 2 blocks/CU (16 waves/CU)
//   regardless (LDS 36.9KB -> 4 blocks; ~176 total regs -> 5 waves/SIMD).
// Predicates: K iff tile <= 7-z; V iff tile <= 8-z (prior band is exactly
//   tile in [t-1,t+1]: delta = 64*(tile-t)-16*wg must lie in [-127,79]).
// out = [ g*(e@V)/E + (1-g)*(p@V)/(P+1e-8) ] / (Sf+1e-8); E,P = sums of
// truncated-bf16 e,p (exactly the MFMA operands).

#define B_ 16
#define L_ 512
#define H_ 8
#define KST 72   // K LDS row stride (shorts)
#define VST 72   // V^T LDS row stride (shorts)
#define WST 36   // We LDS row stride (dwords), 16 rows/wave

typedef __attribute__((ext_vector_type(8))) short bf16x8;
typedef __attribute__((ext_vector_type(4))) float f32x4;
union FR { bf16x8 v; unsigned u[4]; uint4 q4; };

static __device__ __forceinline__ unsigned fbits(float x){union{float f;unsigned u;}c;c.f=x;return c.u;}
static __device__ __forceinline__ float tvf(float x){union{unsigned u;float f;}c;c.u=fbits(x)&0xFFFF0000u;return c.f;}
// pack trunc-bf16(a) | trunc-bf16(b)<<16 in one v_perm_b32
static __device__ __forceinline__ unsigned pk2(float a,float b){return __builtin_amdgcn_perm(fbits(b),fbits(a),0x07060302u);}

// Block barrier with LDS-drain only: does NOT wait vmcnt, so register-staged
// global prefetch loads remain in flight across it (T4). The "memory"
// clobbers fence the compiler from moving LDS/global ops across the barrier.
static __device__ __forceinline__ void barrier_lgkm(){
  asm volatile("s_waitcnt lgkmcnt(0)" ::: "memory");
  __builtin_amdgcn_s_barrier();
  asm volatile("" ::: "memory");
}

__global__ __launch_bounds__(512,2) void anomaly_attn(
    const float* __restrict__ Q, const float* __restrict__ K,
    const float* __restrict__ V, const float* __restrict__ Sig,
    const float* __restrict__ Gate, float* __restrict__ Out)
{
  __shared__ unsigned short Klds[64*KST];   // 9216 B (shared by both l-groups)
  __shared__ unsigned short Vlds[64*VST];   // 9216 B (V^T, granule-swizzled)
  __shared__ unsigned We[8][16][WST];       // 18432 B packed e pairs (wave-private)

  const int tid=threadIdx.x, lane=tid&63, wid=tid>>6, q=lane>>4, c=lane&15;
  const int idx=blockIdx.x, bh=idx&127, z=idx>>7, h=bh&7, b=bh>>3;
  const int grp=wid>>2, wg=wid&3;
  const int t = grp ? (7-z) : z;            // this wave's l-tile
  const int l0w = t*64 + wg*16;             // wave's 16 l-rows: l = l0w + c
  const size_t bh_off = ((size_t)b*L_*H_ + h)*64;
  const float* __restrict__ Qb=Q+bh_off;
  const float* __restrict__ Kb=K+bh_off;
  const float* __restrict__ Vb=V+bh_off;

  // staging roles: threads <256 stage K, threads >=256 stage V
  const bool isK = tid<256;
  const int thr = tid&255;
  const int kr=thr>>2, kcb=thr&3;           // K role: row kr, 16 floats at kcb*16
  const int srp=thr>>3, scb=thr&7;          // V role: rows 2srp..+1, 8 floats at scb*8
  const int swz = (c&3)<<3;                 // We column XOR swizzle
  const int gp=(srp>>2)^scb, rpl=srp&3, vb0i=(gp<<3);  // V pack mapping

  const float* __restrict__ vbase = Vb + (size_t)(2*srp)*512 + scb*8;
  const float* __restrict__ kbase = Kb + (size_t)kr*512 + kcb*16;

  // ---- prologue: load + pack tile 0 by role (always needed) ----
  if (isK) {
    float4 g0=((const float4*)kbase)[0], g1=((const float4*)kbase)[1];
    float4 g2=((const float4*)kbase)[2], g3=((const float4*)kbase)[3];
    uint4 w0,w1;
    w0.x=pk2(g0.x,g0.y); w0.y=pk2(g0.z,g0.w);
    w0.z=pk2(g1.x,g1.y); w0.w=pk2(g1.z,g1.w);
    w1.x=pk2(g2.x,g2.y); w1.y=pk2(g2.z,g2.w);
    w1.z=pk2(g3.x,g3.y); w1.w=pk2(g3.z,g3.w);
    uint4* dst=(uint4*)&Klds[kr*KST + kcb*16];
    dst[0]=w0; dst[1]=w1;
  } else {
    float4 g0=((const float4*)vbase)[0],       g1=((const float4*)vbase)[1];
    float4 g2=((const float4*)(vbase+512))[0], g3=((const float4*)(vbase+512))[1];
    ((unsigned*)&Vlds[(scb*8+0)*VST+vb0i])[rpl]=pk2(g0.x,g2.x);
    ((unsigned*)&Vlds[(scb*8+1)*VST+vb0i])[rpl]=pk2(g0.y,g2.y);
    ((unsigned*)&Vlds[(scb*8+2)*VST+vb0i])[rpl]=pk2(g0.z,g2.z);
    ((unsigned*)&Vlds[(scb*8+3)*VST+vb0i])[rpl]=pk2(g0.w,g2.w);
    ((unsigned*)&Vlds[(scb*8+4)*VST+vb0i])[rpl]=pk2(g1.x,g3.x);
    ((unsigned*)&Vlds[(scb*8+5)*VST+vb0i])[rpl]=pk2(g1.y,g3.y);
    ((unsigned*)&Vlds[(scb*8+6)*VST+vb0i])[rpl]=pk2(g1.z,g3.z);
    ((unsigned*)&Vlds[(scb*8+7)*VST+vb0i])[rpl]=pk2(g1.w,g3.w);
  }

  // ---- Q as B-operand frag: lane c -> l, quad*8+j -> e ----
  bf16x8 qf[2];
  {
    const float* qrow = Qb + (size_t)(l0w+c)*512;
    #pragma unroll
    for (int ks=0; ks<2; ++ks) {
      const float4 a = *(const float4*)(qrow + ks*32 + q*8);
      const float4 d4 = *(const float4*)(qrow + ks*32 + q*8 + 4);
      FR f;
      f.u[0]=pk2(a.x,a.y);  f.u[1]=pk2(a.z,a.w);
      f.u[2]=pk2(d4.x,d4.y); f.u[3]=pk2(d4.z,d4.w);
      qf[ks]=f.v;
    }
  }

  // ---- per-lane prior constants (row l = l0w + c) ----
  const float sgv = Sig[((size_t)b*L_ + l0w + c)*H_ + h];
  float sg = 1.f/(1.f+__expf(-5.f*sgv)) + 1e-5f;
  sg = exp2f(sg*1.5849625007211562f) - 1.f;          // 3^sg - 1
  const float invs = 0.3989422804014327f/sg;
  const float i2s2 = (0.5f/(sg*sg))*1.44269504088896f;

  float eP=0.f, pP=0.f;
  f32x4 accA[4], accB[4];
  #pragma unroll
  for (int n=0;n<4;++n){accA[n]=(f32x4)0.f;accB[n]=(f32x4)0.f;}

  for (int tile=0; tile<8; ++tile) {
    const int s0=tile*64;
    const bool live = tile<=t, diag = tile==t;   // wave-uniform
    const int delta = s0 - l0w;                  // wave-uniform
    // prior band per 32-col chunk (s-l range vs |l-s|<=64 support)
    const bool bk0 = (delta    >= -95) && (delta    <= 79);
    const bool bk1 = (delta+32 >= -95) && (delta+32 <= 79);
    barrier_lgkm();   // barrier A: this tile's K/V packs (prev tail) visible

    // ---- issue tile+1 global loads NOW by role (within-iteration liveness,
    //      no loop-carried PHIs); consumed only after barrier B ----
    float4 g0,g1,g2,g3;
    bool need1=false;
    if (tile<7) {
      need1 = isK ? ((tile+1) <= 7-z) : ((tile+1) <= 8-z);
      if (need1) {
        if (isK) {
          const float* kp = kbase + (size_t)(s0+64)*512;
          g0=((const float4*)kp)[0]; g1=((const float4*)kp)[1];
          g2=((const float4*)kp)[2]; g3=((const float4*)kp)[3];
        } else {
          const float* vp = vbase + (size_t)(s0+64)*512;
          g0=((const float4*)vp)[0];       g1=((const float4*)vp)[1];
          g2=((const float4*)(vp+512))[0]; g3=((const float4*)(vp+512))[1];
        }
      }
    }

    // ---- e path: scores S^T then packed bf16 into We (D-layout == B-layout) ----
    int ks2max = -1;
    if (live) {
      const int ntmax = diag ? wg : 3;          // s-chunks with any e!=0
      ks2max = diag ? (wg>>1) : 1;              // s-32-chunks for PV
      f32x4 sacc[4];
      #pragma unroll
      for (int nt=0;nt<4;++nt) if (nt<=ntmax) {
        f32x4 s=(f32x4)0.f;
        #pragma unroll
        for (int ks=0;ks<2;++ks){
          const bf16x8 kf=*(const bf16x8*)&Klds[(nt*16+c)*KST + ks*32 + q*8];
          s=__builtin_amdgcn_mfma_f32_16x16x32_bf16(kf,qf[ks],s,0,0,0); // A=K(m=s),B=Q(n=l)
        }
        sacc[nt]=s;
      }
      #pragma unroll
      for (int nt=0;nt<4;++nt) {
        if (nt<=ntmax) {
          float ev[4];
          #pragma unroll
          for (int r=0;r<4;++r) ev[r]=exp2f(sacc[nt][r]*0.180336880110323f); // exp(s/8)
          if (diag && nt==wg) {                  // per-element causal mask
            #pragma unroll
            for (int r=0;r<4;++r) if (4*q+r > c) ev[r]=0.f;
          }
          #pragma unroll
          for (int r=0;r<4;++r) eP += tvf(ev[r]);  // sum == MFMA operand
          uint2 w; w.x=pk2(ev[0],ev[1]); w.y=pk2(ev[2],ev[3]);
          *(uint2*)&We[wid][c][(nt*8+2*q)^swz]=w;
        } else if (nt <= 2*ks2max+1) {           // zero-fill read-covered chunk
          uint2 zz; zz.x=0u; zz.y=0u;
          *(uint2*)&We[wid][c][(nt*8+2*q)^swz]=zz;
        }
      }
    }
    asm volatile("s_waitcnt lgkmcnt(0)" ::: "memory");  // We visible (wave-
    // private); "memory" also pins the prefetch loads in the first half.

    // ---- PV frags: e from We; p computed directly in B layout ----
    FR ef[2], pf[2];
    #pragma unroll
    for (int k2=0;k2<2;++k2){
      if (k2<=ks2max) ef[k2].q4 = *(const uint4*)&We[wid][c][(k2*16+4*q)^swz];
      if (k2 ? bk1 : bk0) {
        float pv[8];
        #pragma unroll
        for (int j=0;j<8;++j){
          const float dd=(float)(c - k2*32 - q*8 - j - delta);  // l - s
          pv[j]=invs*exp2f(-dd*dd*i2s2);
          pP += tvf(pv[j]);
        }
        pf[k2].u[0]=pk2(pv[0],pv[1]); pf[k2].u[1]=pk2(pv[2],pv[3]);
        pf[k2].u[2]=pk2(pv[4],pv[5]); pf[k2].u[3]=pk2(pv[6],pv[7]);
      }
    }
    // ---- PV: A = V^T (m=d,k=s), B = W (k=s,n=l) ----
    #pragma unroll
    for (int nd=0;nd<4;++nd){
      const int d=nd*16+c, dg7=(d>>3)&7;
      #pragma unroll
      for (int k2=0;k2<2;++k2){
        const bool pb = k2 ? bk1 : bk0;
        if (k2<=ks2max || pb) {
          const int g2i=((k2<<2)+q)^dg7;
          const bf16x8 vf=*(const bf16x8*)&Vlds[d*VST + (g2i<<3)];
          if (k2<=ks2max) accA[nd]=__builtin_amdgcn_mfma_f32_16x16x32_bf16(vf,ef[k2].v,accA[nd],0,0,0);
          if (pb)         accB[nd]=__builtin_amdgcn_mfma_f32_16x16x32_bf16(vf,pf[k2].v,accB[nd],0,0,0);
        }
      }
    }

    barrier_lgkm();   // barrier B: all waves' K/V reads of this tile complete;
                      // prefetch vmem still in flight (non-draining)

    // ---- write-late: pack tile+1 into K/V LDS (vmcnt wait lands here; the
    //      loads had the whole compute phase to arrive) ----
    if (tile<7 && need1) {
      if (isK) {
        uint4 w0,w1;
        w0.x=pk2(g0.x,g0.y); w0.y=pk2(g0.z,g0.w);
        w0.z=pk2(g1.x,g1.y); w0.w=pk2(g1.z,g1.w);
        w1.x=pk2(g2.x,g2.y); w1.y=pk2(g2.z,g2.w);
        w1.z=pk2(g3.x,g3.y); w1.w=pk2(g3.z,g3.w);
        uint4* dst=(uint4*)&Klds[kr*KST + kcb*16];
        dst[0]=w0; dst[1]=w1;
      } else {
        ((unsigned*)&Vlds[(scb*8+0)*VST+vb0i])[rpl]=pk2(g0.x,g2.x);
        ((unsigned*)&Vlds[(scb*8+1)*VST+vb0i])[rpl]=pk2(g0.y,g2.y);
        ((unsigned*)&Vlds[(scb*8+2)*VST+vb0i])[rpl]=pk2(g0.z,g2.z);
        ((unsigned*)&Vlds[(scb*8+3)*VST+vb0i])[rpl]=pk2(g0.w,g2.w);
        ((unsigned*)&Vlds[(scb*8+4)*VST+vb0i])[rpl]=pk2(g1.x,g3.x);
        ((unsigned*)&Vlds[(scb*8+5)*VST+vb0i])[rpl]=pk2(g1.y,g3.y);
        ((unsigned*)&Vlds[(scb*8+6)*VST+vb0i])[rpl]=pk2(g1.z,g3.z);
        ((unsigned*)&Vlds[(scb*8+7)*VST+vb0i])[rpl]=pk2(g1.w,g3.w);
      }
    }
  }

  // ---- epilogue: quad reduce, per-lane scalars, float4 stores ----
  eP += __shfl_xor(eP,16,64); eP += __shfl_xor(eP,32,64);
  pP += __shfl_xor(pP,16,64); pP += __shfl_xor(pP,32,64);
  float g=Gate[h]; g=1.f/(1.f+__expf(-g));
  const float cA=g/eP;                       // E>0 (diagonal always live)
  const float cB=(1.f-g)/(pP+1e-8f);
  const float Sf=g+(1.f-g)*(pP/(pP+1e-8f));
  const float nf=1.f/(Sf+1e-8f);
  #pragma unroll
  for (int nd=0;nd<4;++nd){
    float4 o;
    o.x=(cA*accA[nd][0]+cB*accB[nd][0])*nf;
    o.y=(cA*accA[nd][1]+cB*accB[nd][1])*nf;
    o.z=(cA*accA[nd][2]+cB*accB[nd][2])*nf;
    o.w=(cA*accA[nd][3]+cB*accB[nd][3])*nf;
    *(float4*)&Out[bh_off + (size_t)(l0w+c)*512 + nd*16 + 4*q] = o;
  }
}

extern "C" void kernel_launch(void* const* d_in, const int* in_sizes, int n_in,
                              void* d_out, int out_size, void* d_ws, size_t ws_size,
                              hipStream_t stream) {
    const float* Q    = (const float*)d_in[0];
    const float* K    = (const float*)d_in[1];
    const float* V    = (const float*)d_in[2];
    const float* Sig  = (const float*)d_in[3];
    const float* Gate = (const float*)d_in[4];
    // d_in[5] = attn_mask: deterministic causal triu — not read.
    float* Out = (float*)d_out;

    dim3 grid(4 * B_ * H_);   // 512 blocks: idx = z*128 + bh; z pairs l-tiles
                              // (z, 7-z) -> every block = 9 live wave-tile
                              // units; same-bh blocks XCD-affine (128%8==0)
    anomaly_attn<<<grid, 512, 0, stream>>>(Q, K, V, Sig, Gate, Out);
}

// Round 6
// 124.310 us; speedup vs baseline: 1.3041x; 1.1591x over previous
//
#include <hip/hip_runtime.h>

// AnomalyAttention: B=16, L=512, H=8, E=D=64. f32 in/out, bf16 MFMA compute.
// Transposed formulation: S^T = K.Q^T (D: row=s, col=l), out^T = V^T.W^T.
// e round-trips LDS as packed bf16 dwords. R9: prior p computed directly in
// B-operand layout per lane. Uniform 8-iteration loop (R5). R12 shape:
// 256-thread blocks, grid 1024 (4/CU-equivalent), per-block l-tile t,
// T14 issue-early/write-late prefetch, no loop-carried staging regs,
// launch_bounds(256,3) (cap ~170: 80 arch + acc fits, no spill), t reversed
// (heavy t=7 blocks dispatch first).
// R15 (K/V DOUBLE-BUFFER -> 1 barrier/iter): R12-R14 established load latency
//   and spill are not the cost; pipes all <30% busy; the residual is
//   per-iteration dependency chains x barrier convergence (16 barriers/block).
//   Dbuf: iter i reads buf[i&1], packs tile i+1 into buf[i&1 ^1]; RAW hazard
//   separated by the single end-of-iter barrier; WAR separated by two
//   barriers automatically (2-buffer rotation). 16 -> 9 barriers/block.
//   LDS 46KB -> 3 blocks/CU (was 4): accepted, reg-occupancy was ~3 anyway.
// R13/R14 ledger: paired 512-thread blocks halve residency via reg footprint
//   (176/wave -> 2 waves/SIMD) -> net negative; reverted.
// out = [ g*(e@V)/E + (1-g)*(p@V)/(P+1e-8) ] / (Sf+1e-8); E,P = sums of
// truncated-bf16 e,p (exactly the MFMA operands).

#define B_ 16
#define L_ 512
#define H_ 8
#define KST 72   // K LDS row stride (shorts)
#define VST 72   // V^T LDS row stride (shorts)
#define WST 36   // We LDS row stride (dwords), 16 rows/wave

typedef __attribute__((ext_vector_type(8))) short bf16x8;
typedef __attribute__((ext_vector_type(4))) float f32x4;
union FR { bf16x8 v; unsigned u[4]; uint4 q4; };

static __device__ __forceinline__ unsigned fbits(float x){union{float f;unsigned u;}c;c.f=x;return c.u;}
static __device__ __forceinline__ float tvf(float x){union{unsigned u;float f;}c;c.u=fbits(x)&0xFFFF0000u;return c.f;}
// pack trunc-bf16(a) | trunc-bf16(b)<<16 in one v_perm_b32
static __device__ __forceinline__ unsigned pk2(float a,float b){return __builtin_amdgcn_perm(fbits(b),fbits(a),0x07060302u);}

// Block barrier with LDS-drain only: does NOT wait vmcnt, so register-staged
// global prefetch loads remain in flight across it (T4). The "memory"
// clobbers fence the compiler from moving LDS/global ops across the barrier.
static __device__ __forceinline__ void barrier_lgkm(){
  asm volatile("s_waitcnt lgkmcnt(0)" ::: "memory");
  __builtin_amdgcn_s_barrier();
  asm volatile("" ::: "memory");
}

__global__ __launch_bounds__(256,3) void anomaly_attn(
    const float* __restrict__ Q, const float* __restrict__ K,
    const float* __restrict__ V, const float* __restrict__ Sig,
    const float* __restrict__ Gate, float* __restrict__ Out)
{
  __shared__ unsigned short Klds[2][64*KST];   // 18432 B (double-buffered)
  __shared__ unsigned short Vlds[2][64*VST];   // 18432 B (V^T, granule-swizzled)
  __shared__ unsigned We[4][16][WST];          // 9216 B packed e pairs (wave-private)

  const int tid=threadIdx.x, lane=tid&63, wid=tid>>6, q=lane>>4, c=lane&15;
  const int idx=blockIdx.x, bh=idx&127, t=7-(idx>>7), h=bh&7, b=bh>>3;
  const int l0w = t*64 + wid*16;            // wave's 16 l-rows: l = l0w + c
  const size_t bh_off = ((size_t)b*L_*H_ + h)*64;
  const float* __restrict__ Qb=Q+bh_off;
  const float* __restrict__ Kb=K+bh_off;
  const float* __restrict__ Vb=V+bh_off;

  const int kr=tid>>2, kcb=tid&3, srp=tid>>3, scb=tid&7;
  const int swz = (c&3)<<3;                 // We column XOR swizzle
  const int gp=(srp>>2)^scb, rpl=srp&3, vb0i=(gp<<3);  // V pack mapping

  // per-thread staging base pointers (add s0*512 per tile)
  const float* __restrict__ vbase = Vb + (size_t)(2*srp)*512 + scb*8;
  const float* __restrict__ kbase = Kb + (size_t)kr*512 + kcb*16;

  // ---- prologue: load + pack tile 0 into buffer 0 (always live) ----
  {
    float4 a0=((const float4*)vbase)[0],       a1=((const float4*)vbase)[1];
    float4 b0=((const float4*)(vbase+512))[0], b1=((const float4*)(vbase+512))[1];
    float4 ka=((const float4*)kbase)[0], kb2=((const float4*)kbase)[1];
    float4 kc2=((const float4*)kbase)[2], kd2=((const float4*)kbase)[3];
    ((unsigned*)&Vlds[0][(scb*8+0)*VST+vb0i])[rpl]=pk2(a0.x,b0.x);
    ((unsigned*)&Vlds[0][(scb*8+1)*VST+vb0i])[rpl]=pk2(a0.y,b0.y);
    ((unsigned*)&Vlds[0][(scb*8+2)*VST+vb0i])[rpl]=pk2(a0.z,b0.z);
    ((unsigned*)&Vlds[0][(scb*8+3)*VST+vb0i])[rpl]=pk2(a0.w,b0.w);
    ((unsigned*)&Vlds[0][(scb*8+4)*VST+vb0i])[rpl]=pk2(a1.x,b1.x);
    ((unsigned*)&Vlds[0][(scb*8+5)*VST+vb0i])[rpl]=pk2(a1.y,b1.y);
    ((unsigned*)&Vlds[0][(scb*8+6)*VST+vb0i])[rpl]=pk2(a1.z,b1.z);
    ((unsigned*)&Vlds[0][(scb*8+7)*VST+vb0i])[rpl]=pk2(a1.w,b1.w);
    uint4 w0,w1;
    w0.x=pk2(ka.x,ka.y);   w0.y=pk2(ka.z,ka.w);
    w0.z=pk2(kb2.x,kb2.y); w0.w=pk2(kb2.z,kb2.w);
    w1.x=pk2(kc2.x,kc2.y); w1.y=pk2(kc2.z,kc2.w);
    w1.z=pk2(kd2.x,kd2.y); w1.w=pk2(kd2.z,kd2.w);
    uint4* dst=(uint4*)&Klds[0][kr*KST + kcb*16];
    dst[0]=w0; dst[1]=w1;
  }

  // ---- Q as B-operand frag: lane c -> l, quad*8+j -> e ----
  bf16x8 qf[2];
  {
    const float* qrow = Qb + (size_t)(l0w+c)*512;
    #pragma unroll
    for (int ks=0; ks<2; ++ks) {
      const float4 a = *(const float4*)(qrow + ks*32 + q*8);
      const float4 d4 = *(const float4*)(qrow + ks*32 + q*8 + 4);
      FR f;
      f.u[0]=pk2(a.x,a.y);  f.u[1]=pk2(a.z,a.w);
      f.u[2]=pk2(d4.x,d4.y); f.u[3]=pk2(d4.z,d4.w);
      qf[ks]=f.v;
    }
  }

  // ---- per-lane prior constants (row l = l0w + c) ----
  const float sgv = Sig[((size_t)b*L_ + l0w + c)*H_ + h];
  float sg = 1.f/(1.f+__expf(-5.f*sgv)) + 1e-5f;
  sg = exp2f(sg*1.5849625007211562f) - 1.f;          // 3^sg - 1
  const float invs = 0.3989422804014327f/sg;
  const float i2s2 = (0.5f/(sg*sg))*1.44269504088896f;

  float eP=0.f, pP=0.f;
  f32x4 accA[4], accB[4];
  #pragma unroll
  for (int n=0;n<4;++n){accA[n]=(f32x4)0.f;accB[n]=(f32x4)0.f;}

  barrier_lgkm();   // publish tile-0 buffers

  for (int tile=0; tile<8; ++tile) {
    const int s0=tile*64, p=tile&1;
    const unsigned short* __restrict__ Krd=&Klds[p][0];
    const unsigned short* __restrict__ Vrd=&Vlds[p][0];
    const bool live = tile<=t, diag = tile==t;   // block-uniform
    const int delta = s0 - l0w;                  // wave-uniform
    // prior band per 32-col chunk (s-l range vs |l-s|<=64 support)
    const bool bk0 = (delta    >= -95) && (delta    <= 79);
    const bool bk1 = (delta+32 >= -95) && (delta+32 <= 79);

    // ---- issue tile+1 global loads NOW (within-iteration liveness, no
    //      loop-carried PHIs); consumed only at the pack below ----
    float4 sva0,sva1,svb0,svb1,ska,skb,skc,skd;
    bool live1=false, vneed1=false;
    if (tile<7) {
      const int d1=delta+64;
      live1 = (tile+1)<=t;
      const bool b0n = (d1    >= -95) && (d1    <= 79);
      const bool b1n = (d1+32 >= -95) && (d1+32 <= 79);
      vneed1 = live1 || b0n || b1n;              // block-uniform in value
      const float* vp = vbase + (size_t)(s0+64)*512;
      const float* kp = kbase + (size_t)(s0+64)*512;
      if (vneed1) {
        sva0=((const float4*)vp)[0];       sva1=((const float4*)vp)[1];
        svb0=((const float4*)(vp+512))[0]; svb1=((const float4*)(vp+512))[1];
      }
      if (live1) {
        ska=((const float4*)kp)[0]; skb=((const float4*)kp)[1];
        skc=((const float4*)kp)[2]; skd=((const float4*)kp)[3];
      }
    }

    // ---- e path: scores S^T then packed bf16 into We (D-layout == B-layout) ----
    int ks2max = -1;
    if (live) {
      const int ntmax = diag ? wid : 3;         // s-chunks with any e!=0
      ks2max = diag ? (wid>>1) : 1;             // s-32-chunks for PV
      f32x4 sacc[4];
      #pragma unroll
      for (int nt=0;nt<4;++nt) if (nt<=ntmax) {
        f32x4 s=(f32x4)0.f;
        #pragma unroll
        for (int ks=0;ks<2;++ks){
          const bf16x8 kf=*(const bf16x8*)&Krd[(nt*16+c)*KST + ks*32 + q*8];
          s=__builtin_amdgcn_mfma_f32_16x16x32_bf16(kf,qf[ks],s,0,0,0); // A=K(m=s),B=Q(n=l)
        }
        sacc[nt]=s;
      }
      #pragma unroll
      for (int nt=0;nt<4;++nt) {
        if (nt<=ntmax) {
          float ev[4];
          #pragma unroll
          for (int r=0;r<4;++r) ev[r]=exp2f(sacc[nt][r]*0.180336880110323f); // exp(s/8)
          if (diag && nt==wid) {                 // per-element causal mask
            #pragma unroll
            for (int r=0;r<4;++r) if (4*q+r > c) ev[r]=0.f;
          }
          #pragma unroll
          for (int r=0;r<4;++r) eP += tvf(ev[r]);  // sum == MFMA operand
          uint2 w; w.x=pk2(ev[0],ev[1]); w.y=pk2(ev[2],ev[3]);
          *(uint2*)&We[wid][c][(nt*8+2*q)^swz]=w;
        } else if (nt <= 2*ks2max+1) {           // zero-fill read-covered chunk
          uint2 zz; zz.x=0u; zz.y=0u;
          *(uint2*)&We[wid][c][(nt*8+2*q)^swz]=zz;
        }
      }
    }
    asm volatile("s_waitcnt lgkmcnt(0)" ::: "memory");  // We visible (wave-
    // private); "memory" also pins the prefetch loads in the first half.

    // ---- PV frags: e from We; p computed directly in B layout ----
    FR ef[2], pf[2];
    #pragma unroll
    for (int k2=0;k2<2;++k2){
      if (k2<=ks2max) ef[k2].q4 = *(const uint4*)&We[wid][c][(k2*16+4*q)^swz];
      if (k2 ? bk1 : bk0) {
        float pv[8];
        #pragma unroll
        for (int j=0;j<8;++j){
          const float dd=(float)(c - k2*32 - q*8 - j - delta);  // l - s
          pv[j]=invs*exp2f(-dd*dd*i2s2);
          pP += tvf(pv[j]);
        }
        pf[k2].u[0]=pk2(pv[0],pv[1]); pf[k2].u[1]=pk2(pv[2],pv[3]);
        pf[k2].u[2]=pk2(pv[4],pv[5]); pf[k2].u[3]=pk2(pv[6],pv[7]);
      }
    }
    // ---- PV: A = V^T (m=d,k=s), B = W (k=s,n=l) ----
    #pragma unroll
    for (int nd=0;nd<4;++nd){
      const int d=nd*16+c, dg7=(d>>3)&7;
      #pragma unroll
      for (int k2=0;k2<2;++k2){
        const bool pb = k2 ? bk1 : bk0;
        if (k2<=ks2max || pb) {
          const int g2i=((k2<<2)+q)^dg7;
          const bf16x8 vf=*(const bf16x8*)&Vrd[d*VST + (g2i<<3)];
          if (k2<=ks2max) accA[nd]=__builtin_amdgcn_mfma_f32_16x16x32_bf16(vf,ef[k2].v,accA[nd],0,0,0);
          if (pb)         accB[nd]=__builtin_amdgcn_mfma_f32_16x16x32_bf16(vf,pf[k2].v,accB[nd],0,0,0);
        }
      }
    }

    // ---- write-late: pack tile+1 into the OTHER buffer (no reader this
    //      iteration; vmcnt wait lands here, covered by the compute above) ----
    if (tile<7) {
      const int pn=p^1;
      if (vneed1) {
        ((unsigned*)&Vlds[pn][(scb*8+0)*VST+vb0i])[rpl]=pk2(sva0.x,svb0.x);
        ((unsigned*)&Vlds[pn][(scb*8+1)*VST+vb0i])[rpl]=pk2(sva0.y,svb0.y);
        ((unsigned*)&Vlds[pn][(scb*8+2)*VST+vb0i])[rpl]=pk2(sva0.z,svb0.z);
        ((unsigned*)&Vlds[pn][(scb*8+3)*VST+vb0i])[rpl]=pk2(sva0.w,svb0.w);
        ((unsigned*)&Vlds[pn][(scb*8+4)*VST+vb0i])[rpl]=pk2(sva1.x,svb1.x);
        ((unsigned*)&Vlds[pn][(scb*8+5)*VST+vb0i])[rpl]=pk2(sva1.y,svb1.y);
        ((unsigned*)&Vlds[pn][(scb*8+6)*VST+vb0i])[rpl]=pk2(sva1.z,svb1.z);
        ((unsigned*)&Vlds[pn][(scb*8+7)*VST+vb0i])[rpl]=pk2(sva1.w,svb1.w);
      }
      if (live1) {
        uint4 w0,w1;
        w0.x=pk2(ska.x,ska.y); w0.y=pk2(ska.z,ska.w);
        w0.z=pk2(skb.x,skb.y); w0.w=pk2(skb.z,skb.w);
        w1.x=pk2(skc.x,skc.y); w1.y=pk2(skc.z,skc.w);
        w1.z=pk2(skd.x,skd.y); w1.w=pk2(skd.z,skd.w);
        uint4* dst=(uint4*)&Klds[pn][kr*KST + kcb*16];
        dst[0]=w0; dst[1]=w1;
      }
    }

    barrier_lgkm();   // the single per-iteration barrier: publishes tile+1
                      // packs; orders this tile's LDS reads before the
                      // next-next overwrite (2-buffer rotation)
  }

  // ---- epilogue: quad reduce, per-lane scalars, float4 stores ----
  eP += __shfl_xor(eP,16,64); eP += __shfl_xor(eP,32,64);
  pP += __shfl_xor(pP,16,64); pP += __shfl_xor(pP,32,64);
  float g=Gate[h]; g=1.f/(1.f+__expf(-g));
  const float cA=g/eP;                       // E>0 (diagonal always live)
  const float cB=(1.f-g)/(pP+1e-8f);
  const float Sf=g+(1.f-g)*(pP/(pP+1e-8f));
  const float nf=1.f/(Sf+1e-8f);
  #pragma unroll
  for (int nd=0;nd<4;++nd){
    float4 o;
    o.x=(cA*accA[nd][0]+cB*accB[nd][0])*nf;
    o.y=(cA*accA[nd][1]+cB*accB[nd][1])*nf;
    o.z=(cA*accA[nd][2]+cB*accB[nd][2])*nf;
    o.w=(cA*accA[nd][3]+cB*accB[nd][3])*nf;
    *(float4*)&Out[bh_off + (size_t)(l0w+c)*512 + nd*16 + 4*q] = o;
  }
}

extern "C" void kernel_launch(void* const* d_in, const int* in_sizes, int n_in,
                              void* d_out, int out_size, void* d_ws, size_t ws_size,
                              hipStream_t stream) {
    const float* Q    = (const float*)d_in[0];
    const float* K    = (const float*)d_in[1];
    const float* V    = (const float*)d_in[2];
    const float* Sig  = (const float*)d_in[3];
    const float* Gate = (const float*)d_in[4];
    // d_in[5] = attn_mask: deterministic causal triu — not read.
    float* Out = (float*)d_out;

    dim3 grid(8 * B_ * H_);   // 1024 blocks: bh = idx&127 (XCD-affine), t reversed
    anomaly_attn<<<grid, 256, 0, stream>>>(Q, K, V, Sig, Gate, Out);
}